// Round 1
// 320.794 us; speedup vs baseline: 1.0208x; 1.0208x over previous
//
#include <hip/hip_runtime.h>
#include <math.h>

#define COL 14
#define NJ 23
#define BATCH 4096
#define NJOINT (BATCH * NJ)              // 94208
#define RADIUS 4
#define THREADS 256
#define BLOCKS 1472                      // 1472 blocks * 4 waves = 5888 waves; 94208/5888 = 16 exactly
#define WAVES_TOTAL (BLOCKS * (THREADS / 64))

__global__ __launch_bounds__(THREADS) void msq3d_kernel(
    const float* __restrict__ o,
    const float* __restrict__ h,
    const float* __restrict__ t,
    const int*   __restrict__ v,
    float* __restrict__ out)
{
    __shared__ float sM[COL * COL];         // M[row*COL + col]
    __shared__ float sColMin[COL], sColMax[COL];
    __shared__ float sWaveSum[THREADS / 64];

    const int tid = threadIdx.x;

    // ---- build Gaussian matrix M once per block (matches scipy reflect) ----
    // (kept byte-identical to the harness-verified version: absmax == 0.0)
    if (tid < COL * COL) {
        double wd[2 * RADIUS + 1];
        double wsum = 0.0;
        #pragma unroll
        for (int k = 0; k <= 2 * RADIUS; ++k) {
            double xx = (double)(k - RADIUS);
            wd[k] = exp(-0.5 * xx * xx);
            wsum += wd[k];
        }
        const int outr = tid / COL, ic = tid % COL;
        float acc = 0.0f;
        #pragma unroll
        for (int k = -RADIUS; k <= RADIUS; ++k) {
            int ii = (outr + k) % (2 * COL);
            if (ii < 0) ii += 2 * COL;
            if (ii >= COL) ii = 2 * COL - 1 - ii;
            if (ii == ic) acc += (float)(wd[k + RADIUS] / wsum);
        }
        sM[outr * COL + ic] = acc;
    }
    __syncthreads();
    if (tid < COL) {
        float mn = sM[tid], mx = mn;
        for (int r = 1; r < COL; ++r) {
            float x = sM[r * COL + tid];
            mn = fminf(mn, x);
            mx = fmaxf(mx, x);
        }
        sColMin[tid] = mn;
        sColMax[tid] = mx;
    }
    __syncthreads();

    const int lane = tid & 63;
    const int wave_in_blk = tid >> 6;
    const int gwave = blockIdx.x * (THREADS / 64) + wave_in_blk;
    const float scale = 1.0f / (float)COL;

    // per-lane static geometry: lane handles elements q0..q0+3 of each 196-elem map
    const bool act = (lane < 49);           // 49 * 4 = 196
    const int q0 = lane * 4;
    int rk[4], ck[4];
    #pragma unroll
    for (int k = 0; k < 4; ++k) {
        int q = q0 + k;
        if (q > COL * COL - 1) q = COL * COL - 1;   // clamp (inactive lanes; avoid OOB LDS addr)
        rk[k] = q / COL;
        ck[k] = q - rk[k] * COL;
    }

    float accD = 0.0f;   // d1 partial on all lanes; d2 folded in on lanes 0..2

    // ---- 2-deep software-pipelined grid-stride loop over joints ----
    // gwave < 5888 <= NJOINT always, so the prologue load is safe.
    int joint = gwave;
    float4 hv4 = make_float4(0.f, 0.f, 0.f, 0.f);
    {
        const float4* hb4 = (const float4*)(h + (size_t)joint * (COL * COL));
        if (act) hv4 = hb4[lane];
    }
    float t0 = t[joint * 3 + 0];
    float t1 = t[joint * 3 + 1];
    float t2 = t[joint * 3 + 2];
    int   v0 = v[joint * 2 + 0];

    for (;;) {
        // ---- issue next joint's loads before touching this joint's data ----
        const int jn = joint + WAVES_TOTAL;
        const bool more = (jn < NJOINT);
        float4 nh4 = make_float4(0.f, 0.f, 0.f, 0.f);
        float nt0 = 0.f, nt1 = 0.f, nt2 = 0.f;
        int   nv0 = 0;
        if (more) {
            const float4* nb4 = (const float4*)(h + (size_t)jn * (COL * COL));
            if (act) nh4 = nb4[lane];
            nt0 = t[jn * 3 + 0];
            nt1 = t[jn * 3 + 1];
            nt2 = t[jn * 3 + 2];
            nv0 = v[jn * 2 + 0];
        }

        // ---- process current joint ----
        const int b = joint / NJ;
        const int j = joint - b * NJ;

        const int xi = (int)truncf(t0 * (float)COL);
        const int yi = (int)truncf(t1 * (float)COL);
        const bool in_range = (xi >= 0) && (xi <= COL - 1) && (yi >= 0) && (yi <= COL - 1);
        const bool mask = (v0 == 1) && in_range;
        const int xc = min(max(xi, 0), COL - 1);
        const int yc = min(max(yi, 0), COL - 1);

        const float hv[4] = {hv4.x, hv4.y, hv4.z, hv4.w};

        // local argmax over this lane's 4 elements (first occurrence)
        float lv = -INFINITY;
        int   lq = 0;
        if (act) {
            #pragma unroll
            for (int k = 0; k < 4; ++k) {
                if (hv[k] > lv) { lv = hv[k]; lq = q0 + k; }
            }
        }

        // d1 accumulation (wave-uniform branch on mask: ~50% skip the tt math)
        if (mask) {
            const float mn  = sColMin[yc] * sColMin[xc];
            const float mx  = sColMax[yc] * sColMax[xc];
            const float inv = 1.0f / (mx - mn);
            if (act) {
                #pragma unroll
                for (int k = 0; k < 4; ++k) {
                    float ttv = (sM[rk[k] * COL + yc] * sM[ck[k] * COL + xc] - mn) * inv;
                    float d = hv[k] - ttv;
                    accD += d * d;
                }
            }
        } else if (act) {
            #pragma unroll
            for (int k = 0; k < 4; ++k)
                accD += hv[k] * hv[k];
        }

        // wave argmax: value-only butterfly max, then ballot picks lowest lane (== first occurrence)
        float wmax = lv;
        #pragma unroll
        for (int off = 1; off < 64; off <<= 1)
            wmax = fmaxf(wmax, __shfl_xor(wmax, off, 64));
        unsigned long long mb = __ballot(act && (lv == wmax));
        const int src = (int)(__ffsll((long long)mb) - 1);
        const int besti = __shfl(lq, src, 64);

        // d2: one o-component per lane (3 parallel scattered loads instead of
        // a serial chain on lane 0). Each lane folds its term into its own accD;
        // the wave reduction below sums them.
        const int by = besti / COL;
        const int bx = besti - by * COL;
        if (lane < 3) {
            const size_t ob = (((size_t)b * (3 * NJ) + j + lane * NJ) * COL + by) * COL + bx;
            const float ov = o[ob];
            const float addv = (lane == 0) ? (float)bx * scale
                             : (lane == 1) ? (float)by * scale : 0.0f;
            const float tc = (lane == 0) ? t0 : (lane == 1) ? t1 : t2;
            const float d = (ov + addv) - tc;
            accD += d * d;
        }

        if (!more) break;
        joint = jn;
        hv4 = nh4;
        t0 = nt0; t1 = nt1; t2 = nt2; v0 = nv0;
    }

    // wave sum reduction
    #pragma unroll
    for (int off = 32; off > 0; off >>= 1)
        accD += __shfl_down(accD, off, 64);
    if (lane == 0) sWaveSum[wave_in_blk] = accD;
    __syncthreads();
    if (tid == 0) {
        float s = 0.0f;
        #pragma unroll
        for (int w = 0; w < THREADS / 64; ++w) s += sWaveSum[w];
        atomicAdd(out, s * (1.0f / (float)NJ));
    }
}

extern "C" void kernel_launch(void* const* d_in, const int* in_sizes, int n_in,
                              void* d_out, int out_size, void* d_ws, size_t ws_size,
                              hipStream_t stream) {
    const float* o = (const float*)d_in[0];
    const float* h = (const float*)d_in[1];
    const float* t = (const float*)d_in[2];
    const int*   v = (const int*)d_in[3];
    float* out = (float*)d_out;

    hipMemsetAsync(d_out, 0, sizeof(float), stream);
    msq3d_kernel<<<BLOCKS, THREADS, 0, stream>>>(o, h, t, v, out);
}